// Round 23
// baseline (64.432 us; speedup 1.0000x reference)
//
#include <hip/hip_runtime.h>

// QuantizedConv2d: N=32, CIN=128, H=W=56, COUT=256, 3x3, pad=1 (zp=-3), stride 1.
// Round 23: r20 (best, 60.8us) + SINGLE-PASS epilogue. r20's 2-pass epilogue
// drains nt stores at each __syncthreads (barrier-drain semantics) -> ~50KB
// store drain serialized mid-epilogue per block. Single-pass: full 64cout x
// 224px tile staged in one 57KB LDS buffer (union w/ A-halo), ONE barrier,
// all 3584 contiguous nt stores issued after the LAST barrier -> drain at
// s_endpgm, overlapped with other blocks. LDS 57KB -> 2 blocks/CU (occupancy
// axis measured flat). Core = r15/r20: 1792x256, acc[7][2], XOR-swizzled
// LDS-A, B global->reg depth-1 prefetch.

typedef __attribute__((ext_vector_type(4))) int i32x4;

#define NB_N 32
#define CIN 128
#define HH 56
#define WW 56
#define PH 58                              // padded H/W
#define COUT 256
#define PIX_PER_IMG (HH*WW)                // 3136
#define X_IMG_INTS (PIX_PER_IMG*CIN)
#define XP_ROW_BYTES (PH*CIN)              // 7424
#define XP_IMG_BYTES (PH*XP_ROW_BYTES)     // 430592
#define XQ_PAD_BYTES ((size_t)NB_N*XP_IMG_BYTES)
#define A_BYTES (6*XP_ROW_BYTES)           // 44544
#define EP_STRIDE 228                      // ints per cout row in epilogue LDS (912 B)
#define LDS_BYTES (64*EP_STRIDE*4)         // 58368 >= A_BYTES

// ---------------- pack_x: NCHW int32 -> padded NHWC int8 (+ fused halo) ----------------
#define WPR 33   // words per w-row (132 B)
__global__ __launch_bounds__(256) void pack_x_kernel(const int* __restrict__ x,
                                                     signed char* __restrict__ xq) {
    __shared__ int tile[WW * WPR];           // 7392 B
    int nh = blockIdx.x;                     // 0..N*H-1
    int n = nh / HH, h = nh - n * HH;
    const int* src = x + (size_t)n * X_IMG_INTS + h * WW;  // (n, c, h, 0)
    signed char* img = xq + (size_t)n * XP_IMG_BYTES;
    int q = threadIdx.x & 15;                // w-quad (0..13 valid)
    int cg4 = threadIdx.x >> 4;              // 0..15
    if (q < 14) {
#pragma unroll
        for (int i = 0; i < 2; ++i) {
            int cg = cg4 + i * 16;           // channel group 0..31
            i32x4 v0 = *(const i32x4*)(src + (cg * 4 + 0) * PIX_PER_IMG + q * 4);
            i32x4 v1 = *(const i32x4*)(src + (cg * 4 + 1) * PIX_PER_IMG + q * 4);
            i32x4 v2 = *(const i32x4*)(src + (cg * 4 + 2) * PIX_PER_IMG + q * 4);
            i32x4 v3 = *(const i32x4*)(src + (cg * 4 + 3) * PIX_PER_IMG + q * 4);
#pragma unroll
            for (int j = 0; j < 4; ++j) {
                int word = (v0[j] & 255) | ((v1[j] & 255) << 8) |
                           ((v2[j] & 255) << 16) | (v3[j] << 24);
                tile[(q * 4 + j) * WPR + cg] = word;
            }
        }
    }
    // fused halo (disjoint bytes from interior writes):
    const i32x4 pad = {(int)0xFDFDFDFD, (int)0xFDFDFDFD, (int)0xFDFDFDFD, (int)0xFDFDFDFD};
    {   // side pads of this row (h+1): w=0 and w=57, 128 B each = 8 x 16B
        int t = threadIdx.x;
        if (t < 16) {
            int w = (t >> 3) ? 57 : 0;
            *(i32x4*)(img + ((size_t)(h + 1) * PH + w) * CIN + (t & 7) * 16) = pad;
        }
    }
    if (h == 0) {       // top pad row 0
        for (int t = threadIdx.x; t < 464; t += 256)
            *(i32x4*)(img + (size_t)t * 16) = pad;
    }
    if (h == HH - 1) {  // bottom pad row 57
        for (int t = threadIdx.x; t < 464; t += 256)
            *(i32x4*)(img + (size_t)57 * XP_ROW_BYTES + t * 16) = pad;
    }
    __syncthreads();
    int* dst = (int*)(img + ((size_t)(h + 1) * PH + 1) * CIN);
#pragma unroll
    for (int i = 0; i < 7; ++i) {
        int t = i * 256 + threadIdx.x;
        int w = t >> 5, c4 = t & 31;
        dst[w * 32 + c4] = tile[w * WPR + c4];
    }
}

// ---------------- pack_w: OIHW int32 -> fragment-ordered int8 ----------------
// frag f = (tap*2 + kb)*16 + nf; byte = f*1024 + lane*16 + j
// -> weight[cout = nf*16 + (lane&15)][cin = kb*64 + (lane>>4)*16 + j][kh][kw]
__global__ __launch_bounds__(256) void pack_w_kernel(const int* __restrict__ w,
                                                     signed char* __restrict__ wq) {
    int idx = blockIdx.x * 256 + threadIdx.x;    // 0..18431
    if (idx >= 9 * 2 * 16 * 64) return;
    int lane = idx & 63;
    int fid = idx >> 6;
    int t = fid / 32;
    int rem = fid - t * 32;
    int kb = rem >> 4;
    int nf = rem & 15;
    int cout = nf * 16 + (lane & 15);
    int cinb = kb * 64 + (lane >> 4) * 16;
    int kh = t / 3, kw = t - kh * 3;
    union { signed char b[16]; i32x4 v; } u;
#pragma unroll
    for (int j = 0; j < 16; ++j) {
        int cin = cinb + j;
        u.b[j] = (signed char)w[((cout * CIN + cin) * 3 + kh) * 3 + kw];
    }
    *(i32x4*)(wq + (size_t)idx * 16) = u.v;
}

// ---------------- conv: LDS-A + global-reg-B implicit GEMM ----------------
// grid = 1792 blocks: img n (32) x rowblk rb (14, 4 rows) x coutblk cq (4, 64 couts).
// wave (pxhalf, chalf): 112 px (7 m-frags) x 32 couts (2 n-frags); acc[7][2].
__global__ __launch_bounds__(256, 2) void conv_kernel(const signed char* __restrict__ xq,
                                                      const signed char* __restrict__ wq,
                                                      const int* __restrict__ bias,
                                                      const float* __restrict__ wscale,
                                                      int* __restrict__ out) {
    __shared__ __align__(16) signed char lds[LDS_BYTES];   // A-halo, then epilogue buffer
    const int tid = threadIdx.x;
    const int lane = tid & 63, wv = tid >> 6;
    const int row = lane & 15, grp = lane >> 4;

    // XCD-chunked swizzle: 1792 = 8*224; consecutive 224 blocks (4 images) per XCD.
    int orig = (blockIdx.x & 7) * 224 + (blockIdx.x >> 3);
    int n = orig / 56;
    int rr = orig - n * 56;
    int rb = rr >> 2;          // row-block: output rows [rb*4, rb*4+4)
    int cq = rr & 3;           // cout quarter: [cq*64, +64)
    int pxhalf = wv >> 1, chalf = wv & 1;

    const signed char* ximg = xq + (size_t)n * XP_IMG_BYTES + (size_t)rb * 4 * XP_ROW_BYTES;

    // ---- prologue: A-halo (6 padded rows) into LDS, swizzled ----
    // LDS[d] = global[g],  g = d ^ (((d>>7)&7)<<4)   (involution on bits 4-6)
#pragma unroll
    for (int k = 0; k < 11; ++k) {
        int d = k * 4096 + tid * 16;
        if (d < A_BYTES) {
            int g = d ^ (((d >> 7) & 7) << 4);
            i32x4 v = *(const i32x4*)(ximg + g);
            *(i32x4*)(lds + d) = v;
        }
    }

    // epilogue constants hoisted before the K-loop
    float sc[2];
    int b2[2];
    const int coutbase = cq * 64 + chalf * 32;
#pragma unroll
    for (int j = 0; j < 2; ++j) {
        int cout = coutbase + j * 16 + row;
        sc[j] = wscale[cout] * 0.5f;          // 0.05/0.1 * ws
        b2[j] = 2 * bias[cout];
    }

    __syncthreads();

    // per-m center pixel index in halo (padded coords, rows 0..5 of halo)
    int pc[7];
#pragma unroll
    for (int m = 0; m < 7; ++m) {
        int off = pxhalf * 112 + m * 16 + row;               // 0..223
        int lr = (off >= 56) + (off >= 112) + (off >= 168);  // off/56
        int w = off - lr * 56;
        pc[m] = (lr + 1) * PH + (w + 1);
    }

    const int tapd[9] = {-PH - 1, -PH, -PH + 1, -1, 0, 1, PH - 1, PH, PH + 1};

    // B direct from global (fragment-ordered, L2-resident), 1-step prefetch.
    const signed char* wbase = wq + (size_t)(cq * 4 + chalf * 2) * 1024 + lane * 16;

    i32x4 acc[7][2] = {};
    i32x4 bn0 = *(const i32x4*)(wbase);
    i32x4 bn1 = *(const i32x4*)(wbase + 1024);

#pragma unroll
    for (int s = 0; s < 18; ++s) {
        const int t = s >> 1, kb = s & 1;
        i32x4 b0 = bn0, b1 = bn1;
        if (s < 17) {   // prefetch next step's B fragments (hidden under 14 MFMAs)
            bn0 = *(const i32x4*)(wbase + (s + 1) * 16384);
            bn1 = *(const i32x4*)(wbase + (s + 1) * 16384 + 1024);
        }
        // A ds_reads (swizzled)
        i32x4 a[7];
#pragma unroll
        for (int m = 0; m < 7; ++m) {
            int pix = pc[m] + tapd[t];
            int g = (pix << 7) + (kb << 6) + (grp << 4);
            int d = g ^ ((pix & 7) << 4);
            a[m] = *(const i32x4*)(lds + d);
        }
#pragma unroll
        for (int m = 0; m < 7; ++m) {
            acc[m][0] = __builtin_amdgcn_mfma_i32_16x16x64_i8(a[m], b0, acc[m][0], 0, 0, 0);
            acc[m][1] = __builtin_amdgcn_mfma_i32_16x16x64_i8(a[m], b1, acc[m][1], 0, 0, 0);
        }
    }

    // ---- epilogue: single pass. quantize -> full-tile LDS -> nt stores LAST ----
    // ep rows: cl = chalf*32 + j*16 + row (0..63), px0 = pxhalf*112 + m*16 + grp*4.
    // All 4 waves write disjoint regions; ONE barrier; stores after it (drain
    // happens at s_endpgm, overlapped with other blocks).
    __syncthreads();                     // all waves done with A-LDS
    int* elds = (int*)lds;
    const int pixbase = rb * 224;
    const size_t nbase = (size_t)n * (COUT * PIX_PER_IMG);
#pragma unroll
    for (int m = 0; m < 7; ++m) {
        int px0 = pxhalf * 112 + m * 16 + grp * 4;
#pragma unroll
        for (int j = 0; j < 2; ++j) {
            int cl = chalf * 32 + j * 16 + row;
            i32x4 v;
#pragma unroll
            for (int r = 0; r < 4; ++r) {
                int o = acc[m][j][r] + b2[j];
                float f = fmaf((float)o, sc[j], 5.0f);
                f = rintf(f);                 // RNE == jnp.round
                f = fminf(fmaxf(f, -128.0f), 127.0f);
                v[r] = (int)f;
            }
            *(i32x4*)(elds + cl * EP_STRIDE + px0) = v;
        }
    }
    __syncthreads();                     // the LAST barrier
    // 3584 tasks = 64 couts x 56 px-quads; contiguous 896B nt runs per cout.
#pragma unroll
    for (int rnd = 0; rnd < 14; ++rnd) {
        int tg = rnd * 256 + tid;
        int cl = tg / 56;
        int q = tg - cl * 56;
        i32x4 v = *(const i32x4*)(elds + cl * EP_STRIDE + q * 4);
        int cout = cq * 64 + cl;
        __builtin_nontemporal_store(v,
            (i32x4*)(out + nbase + (size_t)cout * PIX_PER_IMG + pixbase + q * 4));
    }
}

extern "C" void kernel_launch(void* const* d_in, const int* in_sizes, int n_in,
                              void* d_out, int out_size, void* d_ws, size_t ws_size,
                              hipStream_t stream) {
    const int* x = (const int*)d_in[0];
    const int* w = (const int*)d_in[1];
    const int* bias = (const int*)d_in[2];
    const float* ws = (const float*)d_in[3];
    int* out = (int*)d_out;

    signed char* xq = (signed char*)d_ws;                 // padded NHWC int8
    signed char* wq = xq + XQ_PAD_BYTES;                  // 288 KB fragment-ordered weights

    pack_x_kernel<<<NB_N * HH, 256, 0, stream>>>(x, xq);  // halo fused in
    pack_w_kernel<<<72, 256, 0, stream>>>(w, wq);
    conv_kernel<<<1792, 256, 0, stream>>>(xq, wq, bias, ws, out);
}

// Round 24
// 62.965 us; speedup vs baseline: 1.0233x; 1.0233x over previous
//
#include <hip/hip_runtime.h>

// QuantizedConv2d: N=32, CIN=128, H=W=56, COUT=256, 3x3, pad=1 (zp=-3), stride 1.
// Round 24: r20 (best, 60.8us) + WAVE SKEWING. Diagnosis: conv duration ==
// SUM of pipe times (LDS 17.6 + MFMA 15 + stores 15 ~= 47.6 ~= measured) in
// every config tried -> waves convoy (identical unrolled code, same start =>
// all ds_read together, all MFMA together; phases serialize). Fix: each wave
// traverses the 18 K-steps at offset OFF in {0,5,9,14} (int accumulation is
// order-independent), via template<OFF> so all indices stay compile-time.
// Everything else = r20 verbatim (acc[7][2], (256,3), XOR-swizzled LDS-A,
// depth-1 B prefetch, 2-pass LDS-transpose nontemporal epilogue).

typedef __attribute__((ext_vector_type(4))) int i32x4;

#define NB_N 32
#define CIN 128
#define HH 56
#define WW 56
#define PH 58                              // padded H/W
#define COUT 256
#define PIX_PER_IMG (HH*WW)                // 3136
#define X_IMG_INTS (PIX_PER_IMG*CIN)
#define XP_ROW_BYTES (PH*CIN)              // 7424
#define XP_IMG_BYTES (PH*XP_ROW_BYTES)     // 430592
#define XQ_PAD_BYTES ((size_t)NB_N*XP_IMG_BYTES)
#define A_BYTES (6*XP_ROW_BYTES)           // 44544
#define EP_STRIDE 228                      // ints per cout row in epilogue LDS (912 B)

__device__ constexpr int tapd_c[9] = {-PH - 1, -PH, -PH + 1, -1, 0, 1, PH - 1, PH, PH + 1};

// ---------------- pack_x: NCHW int32 -> padded NHWC int8 (+ fused halo) ----------------
#define WPR 33   // words per w-row (132 B)
__global__ __launch_bounds__(256) void pack_x_kernel(const int* __restrict__ x,
                                                     signed char* __restrict__ xq) {
    __shared__ int tile[WW * WPR];           // 7392 B
    int nh = blockIdx.x;                     // 0..N*H-1
    int n = nh / HH, h = nh - n * HH;
    const int* src = x + (size_t)n * X_IMG_INTS + h * WW;  // (n, c, h, 0)
    signed char* img = xq + (size_t)n * XP_IMG_BYTES;
    int q = threadIdx.x & 15;                // w-quad (0..13 valid)
    int cg4 = threadIdx.x >> 4;              // 0..15
    if (q < 14) {
#pragma unroll
        for (int i = 0; i < 2; ++i) {
            int cg = cg4 + i * 16;           // channel group 0..31
            i32x4 v0 = *(const i32x4*)(src + (cg * 4 + 0) * PIX_PER_IMG + q * 4);
            i32x4 v1 = *(const i32x4*)(src + (cg * 4 + 1) * PIX_PER_IMG + q * 4);
            i32x4 v2 = *(const i32x4*)(src + (cg * 4 + 2) * PIX_PER_IMG + q * 4);
            i32x4 v3 = *(const i32x4*)(src + (cg * 4 + 3) * PIX_PER_IMG + q * 4);
#pragma unroll
            for (int j = 0; j < 4; ++j) {
                int word = (v0[j] & 255) | ((v1[j] & 255) << 8) |
                           ((v2[j] & 255) << 16) | (v3[j] << 24);
                tile[(q * 4 + j) * WPR + cg] = word;
            }
        }
    }
    // fused halo (disjoint bytes from interior writes):
    const i32x4 pad = {(int)0xFDFDFDFD, (int)0xFDFDFDFD, (int)0xFDFDFDFD, (int)0xFDFDFDFD};
    {   // side pads of this row (h+1): w=0 and w=57
        int t = threadIdx.x;
        if (t < 16) {
            int w = (t >> 3) ? 57 : 0;
            *(i32x4*)(img + ((size_t)(h + 1) * PH + w) * CIN + (t & 7) * 16) = pad;
        }
    }
    if (h == 0) {       // top pad row 0
        for (int t = threadIdx.x; t < 464; t += 256)
            *(i32x4*)(img + (size_t)t * 16) = pad;
    }
    if (h == HH - 1) {  // bottom pad row 57
        for (int t = threadIdx.x; t < 464; t += 256)
            *(i32x4*)(img + (size_t)57 * XP_ROW_BYTES + t * 16) = pad;
    }
    __syncthreads();
    int* dst = (int*)(img + ((size_t)(h + 1) * PH + 1) * CIN);
#pragma unroll
    for (int i = 0; i < 7; ++i) {
        int t = i * 256 + threadIdx.x;
        int w = t >> 5, c4 = t & 31;
        dst[w * 32 + c4] = tile[w * WPR + c4];
    }
}

// ---------------- pack_w: OIHW int32 -> fragment-ordered int8 ----------------
// frag f = (tap*2 + kb)*16 + nf; byte = f*1024 + lane*16 + j
// -> weight[cout = nf*16 + (lane&15)][cin = kb*64 + (lane>>4)*16 + j][kh][kw]
__global__ __launch_bounds__(256) void pack_w_kernel(const int* __restrict__ w,
                                                     signed char* __restrict__ wq) {
    int idx = blockIdx.x * 256 + threadIdx.x;    // 0..18431
    if (idx >= 9 * 2 * 16 * 64) return;
    int lane = idx & 63;
    int fid = idx >> 6;
    int t = fid / 32;
    int rem = fid - t * 32;
    int kb = rem >> 4;
    int nf = rem & 15;
    int cout = nf * 16 + (lane & 15);
    int cinb = kb * 64 + (lane >> 4) * 16;
    int kh = t / 3, kw = t - kh * 3;
    union { signed char b[16]; i32x4 v; } u;
#pragma unroll
    for (int j = 0; j < 16; ++j) {
        int cin = cinb + j;
        u.b[j] = (signed char)w[((cout * CIN + cin) * 3 + kh) * 3 + kw];
    }
    *(i32x4*)(wq + (size_t)idx * 16) = u.v;
}

// ---------------- skewed K-loop (compile-time step rotation) ----------------
template<int OFF>
__device__ __forceinline__ void kloop(const signed char* lds, const int* pc,
                                      const signed char* wbase, i32x4 acc[7][2],
                                      int grp) {
    i32x4 bn0 = *(const i32x4*)(wbase + (size_t)OFF * 16384);
    i32x4 bn1 = *(const i32x4*)(wbase + (size_t)OFF * 16384 + 1024);
#pragma unroll
    for (int s = 0; s < 18; ++s) {
        const int sp = (s + OFF) % 18;         // compile-time under full unroll
        const int t = sp >> 1, kb = sp & 1;
        i32x4 b0 = bn0, b1 = bn1;
        if (s < 17) {   // prefetch next step's B fragments
            const int spn = (s + 1 + OFF) % 18;
            bn0 = *(const i32x4*)(wbase + (size_t)spn * 16384);
            bn1 = *(const i32x4*)(wbase + (size_t)spn * 16384 + 1024);
        }
        // A ds_reads (swizzled)
        i32x4 a[7];
#pragma unroll
        for (int m = 0; m < 7; ++m) {
            int pix = pc[m] + tapd_c[t];
            int g = (pix << 7) + (kb << 6) + (grp << 4);
            int d = g ^ ((pix & 7) << 4);
            a[m] = *(const i32x4*)(lds + d);
        }
#pragma unroll
        for (int m = 0; m < 7; ++m) {
            acc[m][0] = __builtin_amdgcn_mfma_i32_16x16x64_i8(a[m], b0, acc[m][0], 0, 0, 0);
            acc[m][1] = __builtin_amdgcn_mfma_i32_16x16x64_i8(a[m], b1, acc[m][1], 0, 0, 0);
        }
    }
}

// ---------------- conv: LDS-A + global-reg-B implicit GEMM ----------------
// grid = 1792 blocks: img n (32) x rowblk rb (14, 4 rows) x coutblk cq (4, 64 couts).
// wave (pxhalf, chalf): 112 px (7 m-frags) x 32 couts (2 n-frags); acc[7][2].
__global__ __launch_bounds__(256, 3) void conv_kernel(const signed char* __restrict__ xq,
                                                      const signed char* __restrict__ wq,
                                                      const int* __restrict__ bias,
                                                      const float* __restrict__ wscale,
                                                      int* __restrict__ out) {
    __shared__ __align__(16) signed char lds[A_BYTES];   // A-halo, then epilogue buffer
    const int tid = threadIdx.x;
    const int lane = tid & 63, wv = tid >> 6;
    const int row = lane & 15, grp = lane >> 4;

    // XCD-chunked swizzle: 1792 = 8*224; consecutive 224 blocks (4 images) per XCD.
    int orig = (blockIdx.x & 7) * 224 + (blockIdx.x >> 3);
    int n = orig / 56;
    int rr = orig - n * 56;
    int rb = rr >> 2;          // row-block: output rows [rb*4, rb*4+4)
    int cq = rr & 3;           // cout quarter: [cq*64, +64)
    int pxhalf = wv >> 1, chalf = wv & 1;

    const signed char* ximg = xq + (size_t)n * XP_IMG_BYTES + (size_t)rb * 4 * XP_ROW_BYTES;

    // ---- prologue: A-halo (6 padded rows) into LDS, swizzled ----
    // LDS[d] = global[g],  g = d ^ (((d>>7)&7)<<4)   (involution on bits 4-6)
#pragma unroll
    for (int k = 0; k < 11; ++k) {
        int d = k * 4096 + tid * 16;
        if (d < A_BYTES) {
            int g = d ^ (((d >> 7) & 7) << 4);
            i32x4 v = *(const i32x4*)(ximg + g);
            *(i32x4*)(lds + d) = v;
        }
    }

    // epilogue constants hoisted before the K-loop
    float sc[2];
    int b2[2];
    const int coutbase = cq * 64 + chalf * 32;
#pragma unroll
    for (int j = 0; j < 2; ++j) {
        int cout = coutbase + j * 16 + row;
        sc[j] = wscale[cout] * 0.5f;          // 0.05/0.1 * ws
        b2[j] = 2 * bias[cout];
    }

    __syncthreads();

    // per-m center pixel index in halo (padded coords, rows 0..5 of halo)
    int pc[7];
#pragma unroll
    for (int m = 0; m < 7; ++m) {
        int off = pxhalf * 112 + m * 16 + row;               // 0..223
        int lr = (off >= 56) + (off >= 112) + (off >= 168);  // off/56
        int w = off - lr * 56;
        pc[m] = (lr + 1) * PH + (w + 1);
    }

    // B direct from global (fragment-ordered, L2-resident), 1-step prefetch.
    const signed char* wbase = wq + (size_t)(cq * 4 + chalf * 2) * 1024 + lane * 16;

    i32x4 acc[7][2] = {};
    // WAVE SKEW: each wave starts the 18-step sequence at a different offset
    // (int accumulation is order-independent) -> breaks the CU-wide convoy.
    if (wv == 0)      kloop<0>(lds, pc, wbase, acc, grp);
    else if (wv == 1) kloop<5>(lds, pc, wbase, acc, grp);
    else if (wv == 2) kloop<9>(lds, pc, wbase, acc, grp);
    else              kloop<14>(lds, pc, wbase, acc, grp);

    // ---- epilogue: quantize -> LDS transpose -> contiguous NONTEMPORAL stores ----
    __syncthreads();                     // all waves done with A-LDS
    int* elds = (int*)lds;
    const int pixbase = rb * 224;
    const size_t nbase = (size_t)n * (COUT * PIX_PER_IMG);
#pragma unroll
    for (int p = 0; p < 2; ++p) {
        if (chalf == p) {
#pragma unroll
            for (int m = 0; m < 7; ++m) {
                int px0 = pxhalf * 112 + m * 16 + grp * 4;
#pragma unroll
                for (int j = 0; j < 2; ++j) {
                    int cl = j * 16 + row;
                    i32x4 v;
#pragma unroll
                    for (int r = 0; r < 4; ++r) {
                        int o = acc[m][j][r] + b2[j];
                        float f = fmaf((float)o, sc[j], 5.0f);
                        f = rintf(f);                 // RNE == jnp.round
                        f = fminf(fmaxf(f, -128.0f), 127.0f);
                        v[r] = (int)f;
                    }
                    *(i32x4*)(elds + cl * EP_STRIDE + px0) = v;
                }
            }
        }
        __syncthreads();
        // all 4 waves: read back rows, nontemporal-store contiguous 896B runs
#pragma unroll
        for (int rnd = 0; rnd < 7; ++rnd) {
            int tg = rnd * 256 + tid;          // 0..1791 = 32 couts x 56 quads
            int cl = tg / 56;
            int q = tg - cl * 56;
            i32x4 v = *(const i32x4*)(elds + cl * EP_STRIDE + q * 4);
            int cout = cq * 64 + p * 32 + cl;
            __builtin_nontemporal_store(v,
                (i32x4*)(out + nbase + (size_t)cout * PIX_PER_IMG + pixbase + q * 4));
        }
        __syncthreads();
    }
}

extern "C" void kernel_launch(void* const* d_in, const int* in_sizes, int n_in,
                              void* d_out, int out_size, void* d_ws, size_t ws_size,
                              hipStream_t stream) {
    const int* x = (const int*)d_in[0];
    const int* w = (const int*)d_in[1];
    const int* bias = (const int*)d_in[2];
    const float* ws = (const float*)d_in[3];
    int* out = (int*)d_out;

    signed char* xq = (signed char*)d_ws;                 // padded NHWC int8
    signed char* wq = xq + XQ_PAD_BYTES;                  // 288 KB fragment-ordered weights

    pack_x_kernel<<<NB_N * HH, 256, 0, stream>>>(x, xq);  // halo fused in
    pack_w_kernel<<<72, 256, 0, stream>>>(w, wq);
    conv_kernel<<<1792, 256, 0, stream>>>(xq, wq, bias, ws, out);
}

// Round 25
// 58.060 us; speedup vs baseline: 1.1097x; 1.0845x over previous
//
#include <hip/hip_runtime.h>

// QuantizedConv2d: N=32, CIN=128, H=W=56, COUT=256, 3x3, pad=1 (zp=-3), stride 1.
// Round 25 (final): r20 verbatim (measured best, 60.8us) + pack_x/pack_w
// merged into ONE launch (block-range partitioned; removes one serial launch
// gap). Plateau ledger: 9 axes flat around this point; pack_x is at HBM
// roofline (64MB/6.3TBps ~= 10.2us); conv ~47us = LDS 17.6 + MFMA 15 +
// store-drain ~15 (non-overlapping at HIP level in this kernel family).

typedef __attribute__((ext_vector_type(4))) int i32x4;

#define NB_N 32
#define CIN 128
#define HH 56
#define WW 56
#define PH 58                              // padded H/W
#define COUT 256
#define PIX_PER_IMG (HH*WW)                // 3136
#define X_IMG_INTS (PIX_PER_IMG*CIN)
#define XP_ROW_BYTES (PH*CIN)              // 7424
#define XP_IMG_BYTES (PH*XP_ROW_BYTES)     // 430592
#define XQ_PAD_BYTES ((size_t)NB_N*XP_IMG_BYTES)
#define A_BYTES (6*XP_ROW_BYTES)           // 44544
#define EP_STRIDE 228                      // ints per cout row in epilogue LDS (912 B)
#define WPR 33                             // words per w-row in pack tile (132 B)
#define PACKX_BLOCKS (NB_N*HH)             // 1792

// ---------------- merged pack: pack_x (+halo) blocks 0..1791, pack_w 1792..1863 ----------------
__global__ __launch_bounds__(256) void pack_kernel(const int* __restrict__ x,
                                                   signed char* __restrict__ xq,
                                                   const int* __restrict__ w,
                                                   signed char* __restrict__ wq) {
    __shared__ int tile[WW * WPR];           // 7392 B (pack_x blocks only)
    if (blockIdx.x >= PACKX_BLOCKS) {
        // ---- pack_w: OIHW int32 -> fragment-ordered int8 ----
        // frag f = (tap*2 + kb)*16 + nf; byte = f*1024 + lane*16 + j
        // -> weight[cout = nf*16 + (lane&15)][cin = kb*64 + (lane>>4)*16 + j][kh][kw]
        int idx = (blockIdx.x - PACKX_BLOCKS) * 256 + threadIdx.x;   // 0..18431
        if (idx < 9 * 2 * 16 * 64) {
            int lane = idx & 63;
            int fid = idx >> 6;
            int t = fid / 32;
            int rem = fid - t * 32;
            int kb = rem >> 4;
            int nf = rem & 15;
            int cout = nf * 16 + (lane & 15);
            int cinb = kb * 64 + (lane >> 4) * 16;
            int kh = t / 3, kw = t - kh * 3;
            union { signed char b[16]; i32x4 v; } u;
#pragma unroll
            for (int j = 0; j < 16; ++j) {
                int cin = cinb + j;
                u.b[j] = (signed char)w[((cout * CIN + cin) * 3 + kh) * 3 + kw];
            }
            *(i32x4*)(wq + (size_t)idx * 16) = u.v;
        }
        return;
    }
    // ---- pack_x: NCHW int32 -> padded NHWC int8 (+ fused halo) ----
    int nh = blockIdx.x;                     // 0..N*H-1
    int n = nh / HH, h = nh - n * HH;
    const int* src = x + (size_t)n * X_IMG_INTS + h * WW;  // (n, c, h, 0)
    signed char* img = xq + (size_t)n * XP_IMG_BYTES;
    int q = threadIdx.x & 15;                // w-quad (0..13 valid)
    int cg4 = threadIdx.x >> 4;              // 0..15
    if (q < 14) {
#pragma unroll
        for (int i = 0; i < 2; ++i) {
            int cg = cg4 + i * 16;           // channel group 0..31
            i32x4 v0 = *(const i32x4*)(src + (cg * 4 + 0) * PIX_PER_IMG + q * 4);
            i32x4 v1 = *(const i32x4*)(src + (cg * 4 + 1) * PIX_PER_IMG + q * 4);
            i32x4 v2 = *(const i32x4*)(src + (cg * 4 + 2) * PIX_PER_IMG + q * 4);
            i32x4 v3 = *(const i32x4*)(src + (cg * 4 + 3) * PIX_PER_IMG + q * 4);
#pragma unroll
            for (int j = 0; j < 4; ++j) {
                int word = (v0[j] & 255) | ((v1[j] & 255) << 8) |
                           ((v2[j] & 255) << 16) | (v3[j] << 24);
                tile[(q * 4 + j) * WPR + cg] = word;
            }
        }
    }
    // fused halo (disjoint bytes from interior writes):
    const i32x4 pad = {(int)0xFDFDFDFD, (int)0xFDFDFDFD, (int)0xFDFDFDFD, (int)0xFDFDFDFD};
    {   // side pads of this row (h+1): w=0 and w=57, 128 B each = 8 x 16B
        int t = threadIdx.x;
        if (t < 16) {
            int wp = (t >> 3) ? 57 : 0;
            *(i32x4*)(img + ((size_t)(h + 1) * PH + wp) * CIN + (t & 7) * 16) = pad;
        }
    }
    if (h == 0) {       // top pad row 0
        for (int t = threadIdx.x; t < 464; t += 256)
            *(i32x4*)(img + (size_t)t * 16) = pad;
    }
    if (h == HH - 1) {  // bottom pad row 57
        for (int t = threadIdx.x; t < 464; t += 256)
            *(i32x4*)(img + (size_t)57 * XP_ROW_BYTES + t * 16) = pad;
    }
    __syncthreads();
    int* dst = (int*)(img + ((size_t)(h + 1) * PH + 1) * CIN);
#pragma unroll
    for (int i = 0; i < 7; ++i) {
        int t = i * 256 + threadIdx.x;
        int wp = t >> 5, c4 = t & 31;
        dst[wp * 32 + c4] = tile[wp * WPR + c4];
    }
}

// ---------------- conv: LDS-A + global-reg-B implicit GEMM ----------------
// grid = 1792 blocks: img n (32) x rowblk rb (14, 4 rows) x coutblk cq (4, 64 couts).
// wave (pxhalf, chalf): 112 px (7 m-frags) x 32 couts (2 n-frags); acc[7][2].
__global__ __launch_bounds__(256, 3) void conv_kernel(const signed char* __restrict__ xq,
                                                      const signed char* __restrict__ wq,
                                                      const int* __restrict__ bias,
                                                      const float* __restrict__ wscale,
                                                      int* __restrict__ out) {
    __shared__ __align__(16) signed char lds[A_BYTES];   // A-halo, then epilogue buffer
    const int tid = threadIdx.x;
    const int lane = tid & 63, wv = tid >> 6;
    const int row = lane & 15, grp = lane >> 4;

    // XCD-chunked swizzle: 1792 = 8*224; consecutive 224 blocks (4 images) per XCD.
    int orig = (blockIdx.x & 7) * 224 + (blockIdx.x >> 3);
    int n = orig / 56;
    int rr = orig - n * 56;
    int rb = rr >> 2;          // row-block: output rows [rb*4, rb*4+4)
    int cq = rr & 3;           // cout quarter: [cq*64, +64)
    int pxhalf = wv >> 1, chalf = wv & 1;

    const signed char* ximg = xq + (size_t)n * XP_IMG_BYTES + (size_t)rb * 4 * XP_ROW_BYTES;

    // ---- prologue: A-halo (6 padded rows) into LDS, swizzled ----
    // LDS[d] = global[g],  g = d ^ (((d>>7)&7)<<4)   (involution on bits 4-6)
#pragma unroll
    for (int k = 0; k < 11; ++k) {
        int d = k * 4096 + tid * 16;
        if (d < A_BYTES) {
            int g = d ^ (((d >> 7) & 7) << 4);
            i32x4 v = *(const i32x4*)(ximg + g);
            *(i32x4*)(lds + d) = v;
        }
    }

    // epilogue constants hoisted before the K-loop
    float sc[2];
    int b2[2];
    const int coutbase = cq * 64 + chalf * 32;
#pragma unroll
    for (int j = 0; j < 2; ++j) {
        int cout = coutbase + j * 16 + row;
        sc[j] = wscale[cout] * 0.5f;          // 0.05/0.1 * ws
        b2[j] = 2 * bias[cout];
    }

    __syncthreads();

    // per-m center pixel index in halo (padded coords, rows 0..5 of halo)
    int pc[7];
#pragma unroll
    for (int m = 0; m < 7; ++m) {
        int off = pxhalf * 112 + m * 16 + row;               // 0..223
        int lr = (off >= 56) + (off >= 112) + (off >= 168);  // off/56
        int w = off - lr * 56;
        pc[m] = (lr + 1) * PH + (w + 1);
    }

    const int tapd[9] = {-PH - 1, -PH, -PH + 1, -1, 0, 1, PH - 1, PH, PH + 1};

    // B direct from global (fragment-ordered, L2-resident), 1-step prefetch.
    const signed char* wbase = wq + (size_t)(cq * 4 + chalf * 2) * 1024 + lane * 16;

    i32x4 acc[7][2] = {};
    i32x4 bn0 = *(const i32x4*)(wbase);
    i32x4 bn1 = *(const i32x4*)(wbase + 1024);

#pragma unroll
    for (int s = 0; s < 18; ++s) {
        const int t = s >> 1, kb = s & 1;
        i32x4 b0 = bn0, b1 = bn1;
        if (s < 17) {   // prefetch next step's B fragments (hidden under 14 MFMAs)
            bn0 = *(const i32x4*)(wbase + (s + 1) * 16384);
            bn1 = *(const i32x4*)(wbase + (s + 1) * 16384 + 1024);
        }
        // A ds_reads (swizzled)
        i32x4 a[7];
#pragma unroll
        for (int m = 0; m < 7; ++m) {
            int pix = pc[m] + tapd[t];
            int g = (pix << 7) + (kb << 6) + (grp << 4);
            int d = g ^ ((pix & 7) << 4);
            a[m] = *(const i32x4*)(lds + d);
        }
#pragma unroll
        for (int m = 0; m < 7; ++m) {
            acc[m][0] = __builtin_amdgcn_mfma_i32_16x16x64_i8(a[m], b0, acc[m][0], 0, 0, 0);
            acc[m][1] = __builtin_amdgcn_mfma_i32_16x16x64_i8(a[m], b1, acc[m][1], 0, 0, 0);
        }
    }

    // ---- epilogue: quantize -> LDS transpose -> contiguous NONTEMPORAL stores ----
    __syncthreads();                     // all waves done with A-LDS
    int* elds = (int*)lds;
    const int pixbase = rb * 224;
    const size_t nbase = (size_t)n * (COUT * PIX_PER_IMG);
#pragma unroll
    for (int p = 0; p < 2; ++p) {
        if (chalf == p) {
#pragma unroll
            for (int m = 0; m < 7; ++m) {
                int px0 = pxhalf * 112 + m * 16 + grp * 4;
#pragma unroll
                for (int j = 0; j < 2; ++j) {
                    int cl = j * 16 + row;
                    i32x4 v;
#pragma unroll
                    for (int r = 0; r < 4; ++r) {
                        int o = acc[m][j][r] + b2[j];
                        float f = fmaf((float)o, sc[j], 5.0f);
                        f = rintf(f);                 // RNE == jnp.round
                        f = fminf(fmaxf(f, -128.0f), 127.0f);
                        v[r] = (int)f;
                    }
                    *(i32x4*)(elds + cl * EP_STRIDE + px0) = v;
                }
            }
        }
        __syncthreads();
        // all 4 waves: read back rows, nontemporal-store contiguous 896B runs
#pragma unroll
        for (int rnd = 0; rnd < 7; ++rnd) {
            int tg = rnd * 256 + tid;          // 0..1791 = 32 couts x 56 quads
            int cl = tg / 56;
            int q = tg - cl * 56;
            i32x4 v = *(const i32x4*)(elds + cl * EP_STRIDE + q * 4);
            int cout = cq * 64 + p * 32 + cl;
            __builtin_nontemporal_store(v,
                (i32x4*)(out + nbase + (size_t)cout * PIX_PER_IMG + pixbase + q * 4));
        }
        __syncthreads();
    }
}

extern "C" void kernel_launch(void* const* d_in, const int* in_sizes, int n_in,
                              void* d_out, int out_size, void* d_ws, size_t ws_size,
                              hipStream_t stream) {
    const int* x = (const int*)d_in[0];
    const int* w = (const int*)d_in[1];
    const int* bias = (const int*)d_in[2];
    const float* ws = (const float*)d_in[3];
    int* out = (int*)d_out;

    signed char* xq = (signed char*)d_ws;                 // padded NHWC int8
    signed char* wq = xq + XQ_PAD_BYTES;                  // 288 KB fragment-ordered weights

    pack_kernel<<<PACKX_BLOCKS + 72, 256, 0, stream>>>(x, xq, w, wq);
    conv_kernel<<<1792, 256, 0, stream>>>(xq, wq, bias, ws, out);
}